// Round 1
// 446.628 us; speedup vs baseline: 1.1561x; 1.1561x over previous
//
#include <hip/hip_runtime.h>
#include <hip/hip_bf16.h>
#include <stdint.h>

// y[b,m,n] = sum_k mask64(a)[b,m,k] * b[b,k,n];  a,b fp32 [8,2048,2048].
// Pipeline: (1) merged convert kernel: A -> bf16 (with 64x64 activity mask),
// B -> bf16 transposed Bt[b,n,k]; (2) bf16 MFMA GEMM, 256x256 tile, BK=64,
// 8 waves, 4-phase-per-K-tile schedule with counted vmcnt(4) (loads stay in
// flight across barriers), setprio(1) around MFMA clusters, XOR-swizzled
// k-half LDS stage units (race-free by construction: every stage lands >=1
// barrier after its target region's last ds_read completion).

#define NBATCH 8
#define MDIM 2048
#define NDIM 2048
#define KDIM 2048
#define THRESH 1e-6f

typedef __attribute__((ext_vector_type(8))) __bf16 bf16x8;
typedef __attribute__((ext_vector_type(4))) float floatx4;
typedef __attribute__((ext_vector_type(8))) unsigned short ushort8v;

__device__ __forceinline__ unsigned short f2bf(float x) {
  union { float f; uint32_t u; } un; un.f = x;
  uint32_t u = un.u;
  return (unsigned short)((u + 0x7FFFu + ((u >> 16) & 1u)) >> 16);  // RNE
}

// ---------------- Kernel 1: merged convert (unchanged from 516us version).
// z in 0..7: A path -> prescan 64x64 tile + fp32->bf16, row-major out.
// z in 8..15: B path -> fp32->bf16 transpose via LDS, Bt[b,n,k] out.
// grid (32, 32, 16), block 256.
__global__ __launch_bounds__(256) void convert_ab(
    const float* __restrict__ A, const float* __restrict__ B,
    unsigned short* __restrict__ Ab, unsigned short* __restrict__ Bt) {
  __shared__ float tileS[64][65];
  const int t = threadIdx.x;
  const int z = blockIdx.z;

  if (z < 8) {
    const int tk = blockIdx.x, tm = blockIdx.y, b = z;
    const int lane = t & 63, wave = t >> 6;
    const float* base =
        A + ((size_t)b * MDIM + tm * 64) * (size_t)KDIM + tk * 64;

    float4 v[2][2];
    float mx = 0.f;
#pragma unroll
    for (int i = 0; i < 2; i++) {
      int e = i * 256 + t;              // ushort8 unit, 0..511
      int r = e >> 3, c8 = (e & 7) << 3;
      v[i][0] = *(const float4*)(base + (size_t)r * KDIM + c8);
      v[i][1] = *(const float4*)(base + (size_t)r * KDIM + c8 + 4);
#pragma unroll
      for (int h = 0; h < 2; h++)
        mx = fmaxf(mx,
                   fmaxf(fmaxf(fabsf(v[i][h].x), fabsf(v[i][h].y)),
                         fmaxf(fabsf(v[i][h].z), fabsf(v[i][h].w))));
    }
#pragma unroll
    for (int off = 32; off > 0; off >>= 1)
      mx = fmaxf(mx, __shfl_down(mx, off, 64));
    if (lane == 0) tileS[0][wave] = mx;
    __syncthreads();
    const bool active = fmaxf(fmaxf(tileS[0][0], tileS[0][1]),
                              fmaxf(tileS[0][2], tileS[0][3])) > THRESH;

    unsigned short* ob =
        Ab + ((size_t)b * MDIM + tm * 64) * (size_t)KDIM + tk * 64;
#pragma unroll
    for (int i = 0; i < 2; i++) {
      int e = i * 256 + t;
      int r = e >> 3, c8 = (e & 7) << 3;
      ushort8v o;
      if (active) {
        o[0] = f2bf(v[i][0].x); o[1] = f2bf(v[i][0].y);
        o[2] = f2bf(v[i][0].z); o[3] = f2bf(v[i][0].w);
        o[4] = f2bf(v[i][1].x); o[5] = f2bf(v[i][1].y);
        o[6] = f2bf(v[i][1].z); o[7] = f2bf(v[i][1].w);
      } else {
#pragma unroll
        for (int j = 0; j < 8; j++) o[j] = 0;
      }
      *(ushort8v*)(ob + (size_t)r * KDIM + c8) = o;  // 16 B store
    }
  } else {
    const int tn = blockIdx.x, tk = blockIdx.y, b = z - 8;
    const float* base =
        B + ((size_t)b * KDIM + tk * 64) * (size_t)NDIM + tn * 64;
#pragma unroll
    for (int i = 0; i < 4; i++) {
      int e = i * 256 + t;
      int r = e >> 4, c4 = (e & 15) << 2;  // r = local k, c4 = local n
      float4 v = *(const float4*)(base + (size_t)r * NDIM + c4);
      tileS[r][c4 + 0] = v.x; tileS[r][c4 + 1] = v.y;
      tileS[r][c4 + 2] = v.z; tileS[r][c4 + 3] = v.w;
    }
    __syncthreads();

    unsigned short* ob =
        Bt + ((size_t)b * NDIM + tn * 64) * (size_t)KDIM + tk * 64;
#pragma unroll
    for (int i = 0; i < 2; i++) {
      int e = i * 256 + t;
      int rn = e >> 3, kc8 = (e & 7) << 3;  // rn = local n, kc8 = local k
      ushort8v o;
#pragma unroll
      for (int j = 0; j < 8; j++) o[j] = f2bf(tileS[kc8 + j][rn]);
      *(ushort8v*)(ob + (size_t)rn * KDIM + kc8) = o;  // 16 B store
    }
  }
}

// ---------------- Kernel 2: bf16 MFMA GEMM, C = A(MxK) * Bt(NxK)^T
// 256x256 tile, BK=64, 8 waves (2Mx4N), per-wave 128x64 output = acc[8][4].
// LDS: [2 buf][2 khalf][256 rows][4 chunks of 16B], khalf unit = 16 KiB.
// Swizzle s(r) = (r&3)^((r>>2)&1): LDS slot of global chunk c at row r is
// c^s(r); writes realized via pre-swizzled global SOURCE (gload_lds dest is
// forced linear: base + lane*16), reads XOR the same involution.
//
// Per K-tile group (4 phases), phase = {ds_read frags; issue 1 k-half stage;
// s_barrier; lgkmcnt(0); setprio(1); 16 MFMA; setprio(0)}:
//   ph0 (mi 0-3, kk0, +B kk0 frags) stage A-k1(t+1) -> other buf
//   ph1 (mi 4-7, kk0)               stage B-k1(t+1) -> other buf
//   ph2 (mi 0-3, kk1, +B kk1 frags) stage B-k0(t+2) -> this buf (free @ph0)
//   ph3 (mi 4-7, kk1)               stage A-k0(t+2) -> this buf (free @ph1)
//   end: s_waitcnt vmcnt(4)  (B-k0/A-k0 of t+2 stay in flight); s_barrier.
// Race-freedom: a region's last ds_reads complete at each wave's lgkmcnt(0)
// (pre-MFMA); the overwriting stage is issued only after a subsequent
// s_barrier, so all waves' reads are architecturally complete first.
#define ASYNC_COPY16(gptr, lptr)                                               \
  __builtin_amdgcn_global_load_lds(                                            \
      (const __attribute__((address_space(1))) void*)(gptr),                   \
      (__attribute__((address_space(3))) void*)(lptr), 16, 0, 0)

__device__ __forceinline__ void stage_half(const unsigned short* __restrict__ g,
                                           unsigned short* l, int tid) {
  // One k-half: 256 rows x 32 bf16 = 1024 x 16B chunks; 2 loads/thread.
#pragma unroll
  for (int i = 0; i < 2; i++) {
    int d = tid + 512 * i;                          // linear LDS chunk
    int r = d >> 2;                                 // row 0..255
    int cc = (d & 3) ^ (r & 3) ^ ((r >> 2) & 1);    // inverse-swizzled source
    ASYNC_COPY16(g + (size_t)r * KDIM + cc * 8, l + (size_t)d * 8);
  }
}

template <bool S2, bool FINAL>
__device__ __forceinline__ void do_group(
    const unsigned short* __restrict__ Ac, const unsigned short* __restrict__ Bc,
    unsigned short* __restrict__ Ao, unsigned short* __restrict__ Bo,
    unsigned short* __restrict__ Ad0, unsigned short* __restrict__ Bd0,
    const unsigned short* __restrict__ Agl, const unsigned short* __restrict__ Bgl,
    int tid, int wm, int wn, int row16, int cx, floatx4 (&acc)[8][4]) {
  bf16x8 bq[2][4];
  bf16x8 af[4];

  // ---- phase 0: (mi 0-3, kk=0) + B kk0 frags; stage A-k1(t+1) -> other buf.
#pragma unroll
  for (int m = 0; m < 4; m++)
    af[m] = *(const bf16x8*)(Ac + (wm + m * 16 + row16) * 32 + cx * 8);
#pragma unroll
  for (int n = 0; n < 4; n++)
    bq[0][n] = *(const bf16x8*)(Bc + (wn + n * 16 + row16) * 32 + cx * 8);
  if (!FINAL) stage_half(Agl + 96, Ao + 8192, tid);
  __builtin_amdgcn_s_barrier();
  asm volatile("s_waitcnt lgkmcnt(0)" ::: "memory");
  __builtin_amdgcn_sched_barrier(0);
  __builtin_amdgcn_s_setprio(1);
#pragma unroll
  for (int m = 0; m < 4; m++)
#pragma unroll
    for (int n = 0; n < 4; n++)
      acc[m][n] = __builtin_amdgcn_mfma_f32_16x16x32_bf16(af[m], bq[0][n],
                                                          acc[m][n], 0, 0, 0);
  __builtin_amdgcn_s_setprio(0);

  // ---- phase 1: (mi 4-7, kk=0); stage B-k1(t+1) -> other buf.
#pragma unroll
  for (int m = 0; m < 4; m++)
    af[m] = *(const bf16x8*)(Ac + (wm + 64 + m * 16 + row16) * 32 + cx * 8);
  if (!FINAL) stage_half(Bgl + 96, Bo + 8192, tid);
  __builtin_amdgcn_s_barrier();
  asm volatile("s_waitcnt lgkmcnt(0)" ::: "memory");
  __builtin_amdgcn_sched_barrier(0);
  __builtin_amdgcn_s_setprio(1);
#pragma unroll
  for (int m = 0; m < 4; m++)
#pragma unroll
    for (int n = 0; n < 4; n++)
      acc[4 + m][n] = __builtin_amdgcn_mfma_f32_16x16x32_bf16(
          af[m], bq[0][n], acc[4 + m][n], 0, 0, 0);
  __builtin_amdgcn_s_setprio(0);

  // ---- phase 2: (mi 0-3, kk=1) + B kk1 frags; stage B-k0(t+2) -> this buf.
#pragma unroll
  for (int m = 0; m < 4; m++)
    af[m] = *(const bf16x8*)(Ac + 8192 + (wm + m * 16 + row16) * 32 + cx * 8);
#pragma unroll
  for (int n = 0; n < 4; n++)
    bq[1][n] = *(const bf16x8*)(Bc + 8192 + (wn + n * 16 + row16) * 32 + cx * 8);
  if (S2) stage_half(Bgl + 128, Bd0, tid);
  __builtin_amdgcn_s_barrier();
  asm volatile("s_waitcnt lgkmcnt(0)" ::: "memory");
  __builtin_amdgcn_sched_barrier(0);
  __builtin_amdgcn_s_setprio(1);
#pragma unroll
  for (int m = 0; m < 4; m++)
#pragma unroll
    for (int n = 0; n < 4; n++)
      acc[m][n] = __builtin_amdgcn_mfma_f32_16x16x32_bf16(af[m], bq[1][n],
                                                          acc[m][n], 0, 0, 0);
  __builtin_amdgcn_s_setprio(0);

  // ---- phase 3: (mi 4-7, kk=1); stage A-k0(t+2) -> this buf.
#pragma unroll
  for (int m = 0; m < 4; m++)
    af[m] = *(const bf16x8*)(Ac + 8192 + (wm + 64 + m * 16 + row16) * 32 +
                             cx * 8);
  if (S2) stage_half(Agl + 128, Ad0, tid);
  __builtin_amdgcn_s_barrier();
  asm volatile("s_waitcnt lgkmcnt(0)" ::: "memory");
  __builtin_amdgcn_sched_barrier(0);
  __builtin_amdgcn_s_setprio(1);
#pragma unroll
  for (int m = 0; m < 4; m++)
#pragma unroll
    for (int n = 0; n < 4; n++)
      acc[4 + m][n] = __builtin_amdgcn_mfma_f32_16x16x32_bf16(
          af[m], bq[1][n], acc[4 + m][n], 0, 0, 0);
  __builtin_amdgcn_s_setprio(0);

  if (!FINAL) {
    if (S2)
      asm volatile("s_waitcnt vmcnt(4)" ::: "memory");  // t+1 resident; t+2
    else                                                // halves in flight
      asm volatile("s_waitcnt vmcnt(0)" ::: "memory");  // epilogue drain
    __builtin_amdgcn_s_barrier();
  }
}

__global__ __launch_bounds__(512, 2) void gemm_bf16_8ph(
    const unsigned short* __restrict__ A, const unsigned short* __restrict__ Bt,
    float* __restrict__ C) {
  // [buf][khalf][256*32] each; A 64 KiB + B 64 KiB = 128 KiB (1 block/CU).
  __shared__ __align__(16) unsigned short AsL[2 * 16384];
  __shared__ __align__(16) unsigned short BsL[2 * 16384];

  const int tid = threadIdx.x;
  const int lane = tid & 63, wave = tid >> 6;
  const int row16 = lane & 15, quad = lane >> 4;
  const int cx = quad ^ (row16 & 3) ^ ((row16 >> 2) & 1);  // read swizzle

  // XCD-aware swizzle: id&7 -> batch (one per XCD); within batch 8x8 tiles,
  // 2x2 supertiles of 4x4, snake.
  const int id = blockIdx.x;
  const int bb = id & 7;
  const int j = id >> 3;          // 0..63
  const int st = j >> 4;          // 0..3
  const int w = j & 15;
  const int str = st >> 1;
  int stc = st & 1;
  if (str & 1) stc ^= 1;
  const int bm = str * 4 + (w >> 2);
  const int bn = stc * 4 + (w & 3);

  const int wr = wave >> 2, wc = wave & 3;
  const int wm = wr * 128, wn = wc * 64;

  const unsigned short* Abase =
      A + (size_t)bb * MDIM * KDIM + (size_t)(bm * 256) * KDIM;
  const unsigned short* Bbase =
      Bt + (size_t)bb * NDIM * KDIM + (size_t)(bn * 256) * KDIM;

  floatx4 acc[8][4];
#pragma unroll
  for (int i = 0; i < 8; i++)
#pragma unroll
    for (int n = 0; n < 4; n++) acc[i][n] = (floatx4){0.f, 0.f, 0.f, 0.f};

  // Prologue: tile0 fully (8 loads) + B-k0/A-k0 of tile1 (4 loads);
  // vmcnt(4) completes the oldest 8 (= tile0), leaves tile1 halves in flight.
  stage_half(Abase + 0, AsL + 0, tid);
  stage_half(Bbase + 0, BsL + 0, tid);
  stage_half(Abase + 32, AsL + 8192, tid);
  stage_half(Bbase + 32, BsL + 8192, tid);
  stage_half(Bbase + 64, BsL + 16384, tid);
  stage_half(Abase + 64, AsL + 16384, tid);
  asm volatile("s_waitcnt vmcnt(4)" ::: "memory");
  __builtin_amdgcn_s_barrier();

  // Main loop: tiles 0..29 (two groups per iteration, buffers alternate).
  for (int it = 0; it < 15; it++) {
    const unsigned short* Agl = Abase + it * 128;
    const unsigned short* Bgl = Bbase + it * 128;
    do_group<true, false>(AsL, BsL, AsL + 16384, BsL + 16384, AsL, BsL, Agl,
                          Bgl, tid, wm, wn, row16, cx, acc);
    do_group<true, false>(AsL + 16384, BsL + 16384, AsL, BsL, AsL + 16384,
                          BsL + 16384, Agl + 64, Bgl + 64, tid, wm, wn, row16,
                          cx, acc);
  }
  // Tile 30: stage only A-k1/B-k1 of tile 31; drain vmcnt(0) at group end.
  do_group<false, false>(AsL, BsL, AsL + 16384, BsL + 16384, AsL, BsL,
                         Abase + 30 * 64, Bbase + 30 * 64, tid, wm, wn, row16,
                         cx, acc);
  // Tile 31: no stages, no end wait.
  do_group<false, true>(AsL + 16384, BsL + 16384, AsL, BsL, AsL + 16384,
                        BsL + 16384, Abase + 31 * 64, Bbase + 31 * 64, tid, wm,
                        wn, row16, cx, acc);

  // Epilogue: D layout col = lane&15, row = quad*4 + reg (m89/m91-verified).
  float* Cb = C + (size_t)bb * MDIM * NDIM;
  const int colBase = bn * 256 + wn + row16;
  const int rowBase = bm * 256 + wm + quad * 4;
#pragma unroll
  for (int mi = 0; mi < 8; mi++) {
#pragma unroll
    for (int ni = 0; ni < 4; ni++) {
      int col = colBase + ni * 16;
      int row = rowBase + mi * 16;
#pragma unroll
      for (int r = 0; r < 4; r++)
        Cb[(size_t)(row + r) * NDIM + col] = acc[mi][ni][r];
    }
  }
}

// ---------------- Fallback: fp32 LDS-tiled GEMM (only if ws too small).
__global__ __launch_bounds__(256) void gemm_f32_fallback(
    const float* __restrict__ A, const float* __restrict__ B,
    float* __restrict__ C) {
  __shared__ float As[64][65];
  __shared__ float Bs[64][65];
  const int tid = threadIdx.x;
  const int tx = tid & 15, ty = tid >> 4;
  const int bn = blockIdx.x, bm = blockIdx.y, bb = blockIdx.z;
  const float* Ab = A + (size_t)bb * MDIM * KDIM + (size_t)(bm * 64) * KDIM;
  const float* Bb = B + (size_t)bb * KDIM * NDIM + bn * 64;

  float acc[4][4] = {};
  for (int k0 = 0; k0 < KDIM; k0 += 64) {
#pragma unroll
    for (int i = 0; i < 4; i++) {
      int e = i * 256 + tid;
      int r = e >> 4, c4 = (e & 15) << 2;
      float4 va = *(const float4*)(Ab + (size_t)r * KDIM + k0 + c4);
      As[r][c4] = va.x; As[r][c4 + 1] = va.y;
      As[r][c4 + 2] = va.z; As[r][c4 + 3] = va.w;
      float4 vb = *(const float4*)(Bb + (size_t)(k0 + r) * NDIM + c4);
      Bs[r][c4] = vb.x; Bs[r][c4 + 1] = vb.y;
      Bs[r][c4 + 2] = vb.z; Bs[r][c4 + 3] = vb.w;
    }
    __syncthreads();
    for (int kk = 0; kk < 64; kk++) {
      float a0[4], b0[4];
#pragma unroll
      for (int i = 0; i < 4; i++) a0[i] = As[ty + 16 * i][kk];
#pragma unroll
      for (int jx = 0; jx < 4; jx++) b0[jx] = Bs[kk][tx + 16 * jx];
#pragma unroll
      for (int i = 0; i < 4; i++)
#pragma unroll
        for (int jx = 0; jx < 4; jx++) acc[i][jx] += a0[i] * b0[jx];
    }
    __syncthreads();
  }
  float* Cb = C + (size_t)bb * MDIM * NDIM;
#pragma unroll
  for (int i = 0; i < 4; i++)
#pragma unroll
    for (int jx = 0; jx < 4; jx++)
      Cb[(size_t)(bm * 64 + ty + 16 * i) * NDIM + bn * 64 + tx + 16 * jx] =
          acc[i][jx];
}

extern "C" void kernel_launch(void* const* d_in, const int* in_sizes, int n_in,
                              void* d_out, int out_size, void* d_ws,
                              size_t ws_size, hipStream_t stream) {
  const float* a = (const float*)d_in[0];
  const float* b = (const float*)d_in[1];
  float* out = (float*)d_out;

  const size_t elems = (size_t)NBATCH * MDIM * KDIM;       // 33.55M
  const size_t need = 2 * elems * sizeof(unsigned short);  // 134.2 MB

  if (ws_size >= need) {
    unsigned short* abf = (unsigned short*)d_ws;
    unsigned short* btf = abf + elems;
    hipLaunchKernelGGL(convert_ab, dim3(32, 32, 16), dim3(256), 0, stream, a,
                       b, abf, btf);
    hipLaunchKernelGGL(gemm_bf16_8ph, dim3(512), dim3(512), 0, stream, abf,
                       btf, out);
  } else {
    hipLaunchKernelGGL(gemm_f32_fallback, dim3(32, 32, NBATCH), dim3(256), 0,
                       stream, a, b, out);
  }
}